// Round 17
// baseline (368.269 us; speedup 1.0000x reference)
//
#include <hip/hip_runtime.h>
#include <math.h>

#define N   2048
#define NT  512
#define V   4     // elements per thread; N == NT*V
#define VSH 2     // log2(V)

// wave-local compiler fence: no HW instruction. Same-wave DS ops complete
// in issue order on CDNA, so cross-lane LDS visibility within one wave
// needs only a compiler reorder/cache fence.
#define WAVE_FENCE() do { __builtin_amdgcn_wave_barrier(); \
                          asm volatile("" ::: "memory"); } while (0)

// exact integer block weight: sum_{j=h}^{e} (N-j)  (< 2^22, exact in fp32)
__device__ __forceinline__ int wsum(int h, int e) {
    return (((N - h) + (N - e)) * (e - h + 1)) >> 1;
}

// padded LDS index: +1 word every 32 -> conflict-free structured access
__device__ __forceinline__ int pidx(int j) { return j + (j >> 5); }

// float -> u32 key; ascending key == descending theta. Exactly invertible.
__device__ __forceinline__ unsigned desc_key(float t) {
    unsigned u = __float_as_uint(t);
    unsigned a = (u & 0x80000000u) ? ~u : (u ^ 0x80000000u);
    return ~a;
}
__device__ __forceinline__ float decode_key(unsigned d) {
    unsigned a = ~d;
    unsigned u = (a & 0x80000000u) ? (a ^ 0x80000000u) : ~a;
    return __uint_as_float(u);
}

// R15 (validated R6): sort key with embedded origin. Top 21 bits = RN-
// quantized desc_key (monotone); low 11 bits = original index (stable
// tie-break -> all keys UNIQUE). Provenance rides through the sort.

// packed stack entry: Y fp32 (RN to 21-bit mantissa) | 11-bit block head.
#define INVALID_P 0xFFFFFFFFu
__device__ __forceinline__ unsigned packYH(float Y, int h) {
    return ((__float_as_uint(Y) + 0x400u) & 0xFFFFF800u) | (unsigned)h;
}
__device__ __forceinline__ float upY(unsigned u) { return __uint_as_float(u & 0xFFFFF800u); }
__device__ __forceinline__ int   upH(unsigned u) { return (int)(u & 0x7FFu); }

// ---- register bitonic helpers ----------------------------------------------
__device__ __forceinline__ void ceu(unsigned &a, unsigned &b, bool up) {
    unsigned mn = (a < b) ? a : b;
    unsigned mx = (a < b) ? b : a;
    a = up ? mn : mx;
    b = up ? mx : mn;
}

// R18 (validated R9): ascending-only CE with key-inversion normalization —
// sorted ORDER identical (unique keys) at half the CE cost.
__device__ __forceinline__ void cea(unsigned &a, unsigned &b) {
    unsigned mn = (a < b) ? a : b;
    unsigned mx = (a < b) ? b : a;
    a = mn; b = mx;
}

__device__ __forceinline__ void merge4a(unsigned* r) {
    cea(r[0], r[2]); cea(r[1], r[3]);
    cea(r[0], r[1]); cea(r[2], r[3]);
}

__device__ __forceinline__ void shfl_ce(unsigned* r, int d, bool keepMin) {
    #pragma unroll
    for (int q = 0; q < V; ++q) {
        unsigned p = __shfl_xor(r[q], d, 64);
        bool lt = r[q] < p;
        r[q] = (lt == keepMin) ? r[q] : p;
    }
}

// next block head after (lane, d) within lanes [.., bEnd); bEnd*V if none
__device__ __forceinline__ int next_head_p(const unsigned* sU,
                                           const unsigned char* sBeg,
                                           const unsigned char* sEnd,
                                           int lane, int d, int bEnd)
{
    if (d + 1 < (int)sEnd[lane]) return upH(sU[(d + 1) * NT + lane]);
    for (int l = lane + 1; l < bEnd; ++l)
        if (sBeg[l] != sEnd[l]) return upH(sU[(int)sBeg[l] * NT + l]);
    return bEnd << VSH;   // bEnd * V
}

// ============================================================================
// R26 = R25 structure re-decomposed at NT=512 / V=4.
//   R16 diagnosis: static VALU work ~56us vs VALUBusy-time 144us -> the
//   kernel is DEPENDENCY-LATENCY-bound (sort's ~270-deep serial CE/shfl
//   chain per thread at ~4.6 blocks/CU), not issue-bound. Lever: halve the
//   per-thread chain (V=4) and raise wave count (512-thr blocks, (512,6) ->
//   3 blocks x 8 waves = 24 waves/CU vs ~18). Costs: 6 LDS exchange stages
//   (vs 3, +6 barriers ~ +1.5us, LDS BW free) and a 9-level merge tree.
//   Sorted order identical (unique keys); PAV solution unique regardless of
//   merge association; Y-sum reorder ulps absorbed by 21-bit quantization.
// Carried (validated R6-R16): idx-embedded qkeys; ascending-only normalized
// sort; load-time orig keys; searchless scatter unsort via s_inv;
// zero-scratch expansion; rank = exp(theta)[moments] x blockscale[bwd];
// wave-local merge sync lev<=4 regions; ph1-row L2 prefetch; firstEx peel.
// ============================================================================
__global__ void __launch_bounds__(NT, 6)
fused_kernel(const float* __restrict__ x1, const float* __restrict__ x2,
             float* __restrict__ out)
{
    __shared__ unsigned       s_kx[N + (N >> 5)];  // orig keys -> governing -> scales
    __shared__ unsigned       s_u [N + (N >> 5)];  // sort exchange -> PAV stacks
    __shared__ unsigned short s_inv[N];            // orig idx -> sorted pos
    __shared__ unsigned char  sBeg[NT], sEnd[NT];
    __shared__ float          s_red[NT / 64][5];
    __shared__ unsigned       swF[NT / 64];
    __shared__ int            swB[NT / 64];

    float* s_kxf = (float*)s_kx;

    const int p    = blockIdx.x;
    const int tid  = threadIdx.x;
    const int lane = tid & 63;
    const int wid  = tid >> 6;

    float S1 = 0.f, Q1 = 0.f, S2 = 0.f, Q2 = 0.f, P = 0.f;
    float rv1[V];

    for (int ph = 0; ph < 2; ++ph) {
        const float* __restrict__ x = ph ? x2 : x1;
        const size_t base = (size_t)p * N;

        // ---- load; orig full keys -> s_kx (own cells); qkeys -> r ----
        const float4* __restrict__ xv = (const float4*)(x + base + tid * V);
        float4 a0 = xv[0];

        if (ph == 0) {
            // L2 prefetch of the ph1 row: touch + sink, no live state.
            const float4* __restrict__ pv = (const float4*)(x2 + base + tid * V);
            float4 p0 = pv[0];
            asm volatile("" :: "v"(p0.x), "v"(p0.w));
        }

        const int bse = tid * V;
        unsigned dk[V];
        dk[0] = desc_key(a0.x * 10.0f); dk[1] = desc_key(a0.y * 10.0f);
        dk[2] = desc_key(a0.z * 10.0f); dk[3] = desc_key(a0.w * 10.0f);
        unsigned r[V];
        #pragma unroll
        for (int q = 0; q < V; ++q) {
            s_kx[pidx(bse + q)] = dk[q];
            r[q] = ((dk[q] + 0x400u) & 0xFFFFF800u) | (unsigned)(bse + q);
        }

        // ---- bitonic sort: k=2 in-thread (compile-time dirs) ----
        ceu(r[0], r[1], true);  ceu(r[2], r[3], false);   // bitonic quad

        // enter normalized space for k=4 completion (dir bit = tid&1)
        unsigned m = ((tid & 1) == 0) ? 0u : 0xFFFFFFFFu;
        #pragma unroll
        for (int q = 0; q < V; ++q) r[q] ^= m;
        merge4a(r);

        bool firstEx = true;
        #pragma unroll
        for (int kk = 3; kk <= 11; ++kk) {
            // k = 1<<kk; dir bit = tid & (k/V) = tid & (1<<(kk-2))
            const unsigned mn_ = ((tid & (1 << (kk - 2))) == 0) ? 0u : 0xFFFFFFFFu;
            const unsigned dm = m ^ mn_;
            m = mn_;
            #pragma unroll
            for (int q = 0; q < V; ++q) r[q] ^= dm;
            #pragma unroll
            for (int jb = kk - 1; jb >= VSH; --jb) {
                const int d = 1 << (jb - VSH);       // thread distance
                if (d >= 64) {
                    if (!firstEx) __syncthreads();   // peel: first exchange's
                    firstEx = false;                 // buffer has no prior readers
                    #pragma unroll
                    for (int q = 0; q < V; ++q) s_u[pidx(tid * V + q)] = r[q];
                    __syncthreads();
                    const bool keepMin = ((tid & d) == 0);
                    const int ptid = tid ^ d;
                    #pragma unroll
                    for (int q = 0; q < V; ++q) {
                        unsigned pv = s_u[pidx(ptid * V + q)];
                        bool lt = r[q] < pv;
                        r[q] = (lt == keepMin) ? r[q] : pv;
                    }
                } else {
                    shfl_ce(r, d, (tid & d) == 0);
                }
            }
            merge4a(r);
        }
        // kk=11 dir bit tid&512 == 0 for all tid<512 -> m ends at 0:
        // keys in plain space, fully ascending-sorted.

        __syncthreads();   // drain last exchange readers (s_u reused next)

        // ---- PAV phase 1: true thetas via idx gather; inv-perm scatter ----
        {
            unsigned fkv[V];
            #pragma unroll
            for (int k = 0; k < V; ++k) {
                const int idx = (int)(r[k] & 0x7FFu);
                fkv[k] = s_kx[pidx(idx)];                    // ILP gather
                s_inv[idx] = (unsigned short)(bse + k);      // inverse perm
            }
            float eY[V];
            #pragma unroll
            for (int k = 0; k < V; ++k) eY[k] = __expf(decode_key(fkv[k]));

            int   sp = 0;
            float t0Y = 0.f, t1Y = 0.f;
            int   t0h = 0,   t1h = 0;
            #pragma unroll
            for (int k = 0; k < V; ++k) {
                const int j = bse + k;
                float cY = eY[k];
                int   ch = j;
                while (sp > 0) {
                    float cW = (float)wsum(ch, j);
                    float tW = (float)wsum(t0h, ch - 1);
                    if (t0Y * cW > cY * tW) break;        // strictly decreasing
                    cY += t0Y; ch = t0h;
                    --sp;
                    t0Y = t1Y; t0h = t1h;
                    if (sp > 1) {
                        unsigned u = s_u[(sp - 2) * NT + tid];
                        t1Y = upY(u); t1h = upH(u);
                    }
                }
                s_u[sp * NT + tid] = packYH(cY, ch);
                t1Y = t0Y; t1h = t0h;
                t0Y = cY;  t0h = ch;
                ++sp;
            }
            sBeg[tid] = 0; sEnd[tid] = (unsigned char)sp;
        }
        // PAV-1 state consumed by lev 0-5 is wave-local (regions <= 1 wave,
        // wave-aligned). Cross-wave readers covered by the real barriers
        // below. Compiler fence only:
        WAVE_FENCE();

        // ---- PAV phase 2: merge tree, 9 levels (NT=512) ----
        // lev 0-5: regions (2g<=64) wave-contained -> WAVE_FENCE.
        // lev 6,7,8: cross-wave -> real __syncthreads (placed after lev>=5).
        for (int lev = 0; lev < 9; ++lev) {
            const int g = 1 << lev;
            if ((tid & (2 * g - 1)) == 0) {
                const int a = tid, mid = tid + g, b = tid + 2 * g;
                int l0 = mid - 1;
                while (l0 >= a && sBeg[l0] == sEnd[l0]) --l0;
                int l1 = mid;
                while (l1 < b && sBeg[l1] == sEnd[l1]) ++l1;
                if (l0 >= a && l1 < b) {
                    int d0 = (int)sEnd[l0] - 1;
                    unsigned tu = s_u[d0 * NT + l0];
                    float tY = upY(tu); int th_ = upH(tu);
                    int te = (mid << VSH) - 1;
                    int d1 = (int)sBeg[l1];
                    unsigned cu = s_u[d1 * NT + l1];
                    float cY = upY(cu); int ch = upH(cu);
                    int ce = next_head_p(s_u, sBeg, sEnd, l1, d1, b) - 1;
                    if (!(tY * (float)wsum(ch, ce) > cY * (float)wsum(th_, te))) {
                        sBeg[l1] = (unsigned char)(d1 + 1);   // consume G1 front
                        for (;;) {
                            if (l0 >= a &&
                                !(tY * (float)wsum(ch, ce) > cY * (float)wsum(th_, te))) {
                                cY += tY; ch = th_;           // absorb G0 top
                                sEnd[l0] = (unsigned char)((int)sEnd[l0] - 1);
                                if (sBeg[l0] == sEnd[l0]) {
                                    do { --l0; } while (l0 >= a && sBeg[l0] == sEnd[l0]);
                                }
                                if (l0 >= a) {
                                    int dd = (int)sEnd[l0] - 1;
                                    unsigned uu = s_u[dd * NT + l0];
                                    tY = upY(uu); te = th_ - 1; th_ = upH(uu);
                                }
                                continue;
                            }
                            while (l1 < b && sBeg[l1] == sEnd[l1]) ++l1;
                            if (l1 < b) {                      // absorb next G1 block?
                                int dn = (int)sBeg[l1];
                                unsigned nu = s_u[dn * NT + l1];
                                float nY = upY(nu); int nh = upH(nu);
                                int ne = next_head_p(s_u, sBeg, sEnd, l1, dn, b) - 1;
                                if (!(cY * (float)wsum(nh, ne) > nY * (float)wsum(ch, ce))) {
                                    cY += nY; ce = ne;
                                    sBeg[l1] = (unsigned char)(dn + 1);
                                    continue;
                                }
                            }
                            break;
                        }
                        int lh = ch >> VSH;                    // push at head's lane
                        if (ch >= (mid << VSH)) {              // head in G1 -> front
                            int nb = (int)sBeg[lh] - 1;
                            sBeg[lh] = (unsigned char)nb;
                            s_u[nb * NT + lh] = packYH(cY, ch);
                        } else {                               // head in G0 -> tail
                            int nb2 = (int)sEnd[lh];
                            s_u[nb2 * NT + lh] = packYH(cY, ch);
                            sEnd[lh] = (unsigned char)(nb2 + 1);
                        }
                    }
                }
            }
            if (lev >= 5) __syncthreads();   // before lev6..8 and after lev8
            else          WAVE_FENCE();      // wave-local levels: free fence
        }

        // ---- divergence-free expansion (stacks read directly from s_u) ----
        const int b0 = sBeg[tid], b1 = sEnd[tid];
        unsigned myLast  = (b1 > b0) ? s_u[(b1 - 1) * NT + tid] : INVALID_P;
        int      myFirst = (b1 > b0) ? upH(s_u[b0 * NT + tid]) : N;

        // forward wave scan: rightmost valid packed entry among lanes <= lane
        unsigned fv = myLast;
        #pragma unroll
        for (int off = 1; off < 64; off <<= 1) {
            unsigned o = (unsigned)__shfl_up((int)fv, off);
            if (fv == INVALID_P) fv = o;
        }
        unsigned cF = (unsigned)__shfl_up((int)fv, 1);
        if (lane == 0) cF = INVALID_P;
        // backward wave scan: leftmost head among lanes >= lane
        int bv = myFirst;
        #pragma unroll
        for (int off = 1; off < 64; off <<= 1) {
            int o = __shfl_down(bv, off);
            if (bv == N) bv = o;
        }
        int cB = __shfl_down(bv, 1);
        if (lane == 63) cB = N;
        if (lane == 63) swF[wid] = fv;
        if (lane == 0)  swB[wid] = bv;
        __syncthreads();
        if (cF == INVALID_P)
            for (int w = wid - 1; w >= 0; --w)
                if (swF[w] != INVALID_P) { cF = swF[w]; break; }
        if (cB == N)
            for (int w = wid + 1; w < NT / 64; ++w)
                if (swB[w] != N) { cB = swB[w]; break; }

        // fwd pass: governing packed (h,Y) per position -> s_kx (keys dead)
        {
            int dptr = b0;
            int nxtOwn = (dptr < b1) ? upH(s_u[dptr * NT + tid]) : N;
            unsigned cur = cF;
            #pragma unroll
            for (int q = 0; q < V; ++q) {
                int j = bse + q;
                if (j == nxtOwn) {
                    cur = s_u[dptr * NT + tid];
                    ++dptr;
                    nxtOwn = (dptr < b1) ? upH(s_u[dptr * NT + tid]) : N;
                }
                s_kx[pidx(j)] = cur;
            }
        }
        // bwd pass: block SCALE c = W/Y written IN PLACE over governing.
        // (exp(theta) re-attached in moments pass — bit-identical product.)
        {
            int dptr2 = b1 - 1;
            int h2 = (dptr2 >= b0) ? upH(s_u[dptr2 * NT + tid]) : -1;
            int nxt = cB;
            #pragma unroll
            for (int q = V - 1; q >= 0; --q) {
                int j = bse + q;
                int e = nxt - 1;
                unsigned cu = s_kx[pidx(j)];
                s_kxf[pidx(j)] = (float)wsum(upH(cu), e) / upY(cu);
                if (j == h2) {
                    nxt = j; --dptr2;
                    h2 = (dptr2 >= b0) ? upH(s_u[dptr2 * NT + tid]) : -1;
                }
            }
        }
        __syncthreads();

        // ---- moments: own-origin gather; rank = exp(theta_own) * scale ----
        {
            float4 c0 = xv[0];
            float xx[V] = {c0.x, c0.y, c0.z, c0.w};
            #pragma unroll
            for (int q = 0; q < V; ++q) {
                int jq = (int)s_inv[bse + q];
                float rv = __expf(xx[q] * 10.0f) * s_kxf[pidx(jq)];
                if (ph == 0) {
                    rv1[q] = rv;
                    S1 += rv; Q1 += rv * rv;
                } else {
                    S2 += rv; Q2 += rv * rv; P += rv1[q] * rv;
                }
            }
        }
        __syncthreads();   // protect s_kx/s_u/s_inv before next phase
    }

    // ---- block reduction of the 5 moments ----
    #pragma unroll
    for (int off = 32; off > 0; off >>= 1) {
        S1 += __shfl_down(S1, off);
        Q1 += __shfl_down(Q1, off);
        S2 += __shfl_down(S2, off);
        Q2 += __shfl_down(Q2, off);
        P  += __shfl_down(P,  off);
    }
    if (lane == 0) {
        s_red[wid][0] = S1; s_red[wid][1] = Q1; s_red[wid][2] = S2;
        s_red[wid][3] = Q2; s_red[wid][4] = P;
    }
    __syncthreads();
    if (tid == 0) {
        for (int w = 1; w < NT / 64; ++w) {
            S1 += s_red[w][0]; Q1 += s_red[w][1]; S2 += s_red[w][2];
            Q2 += s_red[w][3]; P  += s_red[w][4];
        }
        const float inv_n = 1.0f / (float)N;
        float num = P  - S1 * S2 * inv_n;
        float d1  = Q1 - S1 * S1 * inv_n;
        float d2  = Q2 - S2 * S2 * inv_n;
        out[p] = 1.0f - num / sqrtf(d1 * d2);
    }
}

extern "C" void kernel_launch(void* const* d_in, const int* in_sizes, int n_in,
                              void* d_out, int out_size, void* d_ws, size_t ws_size,
                              hipStream_t stream) {
    const float* x1 = (const float*)d_in[0];
    const float* x2 = (const float*)d_in[1];
    float* out = (float*)d_out;
    const int nrows = in_sizes[0] / N;        // 4096 row pairs
    fused_kernel<<<nrows, NT, 0, stream>>>(x1, x2, out);
}

// Round 19
// 260.677 us; speedup vs baseline: 1.4127x; 1.4127x over previous
//
#include <hip/hip_runtime.h>
#include <math.h>

#define N   2048
#define NT  256
#define V   8     // elements per thread; N == NT*V

// wave-local compiler fence: no HW instruction. Same-wave DS ops complete
// in issue order on CDNA, so cross-lane LDS visibility within one wave
// needs only a compiler reorder/cache fence.
#define WAVE_FENCE() do { __builtin_amdgcn_wave_barrier(); \
                          asm volatile("" ::: "memory"); } while (0)

// exact integer block weight: sum_{j=h}^{e} (N-j)  (< 2^22, exact in fp32)
__device__ __forceinline__ int wsum(int h, int e) {
    return (((N - h) + (N - e)) * (e - h + 1)) >> 1;
}

// padded LDS index: +1 word every 32 -> conflict-free structured access
__device__ __forceinline__ int pidx(int j) { return j + (j >> 5); }

// float -> u32 key; ascending key == descending theta. Exactly invertible.
__device__ __forceinline__ unsigned desc_key(float t) {
    unsigned u = __float_as_uint(t);
    unsigned a = (u & 0x80000000u) ? ~u : (u ^ 0x80000000u);
    return ~a;
}
__device__ __forceinline__ float decode_key(unsigned d) {
    unsigned a = ~d;
    unsigned u = (a & 0x80000000u) ? (a ^ 0x80000000u) : ~a;
    return __uint_as_float(u);
}

// R15 (validated R6): sort key with embedded origin. Top 21 bits = RN-
// quantized desc_key (monotone); low 11 bits = original index (stable
// tie-break -> all keys UNIQUE). Provenance rides through the sort.

// packed stack entry: Y fp32 (RN to 21-bit mantissa) | 11-bit block head.
#define INVALID_P 0xFFFFFFFFu
__device__ __forceinline__ unsigned packYH(float Y, int h) {
    return ((__float_as_uint(Y) + 0x400u) & 0xFFFFF800u) | (unsigned)h;
}
__device__ __forceinline__ float upY(unsigned u) { return __uint_as_float(u & 0xFFFFF800u); }
__device__ __forceinline__ int   upH(unsigned u) { return (int)(u & 0x7FFu); }

// ---- register bitonic helpers ----------------------------------------------
__device__ __forceinline__ void ceu(unsigned &a, unsigned &b, bool up) {
    unsigned mn = (a < b) ? a : b;
    unsigned mx = (a < b) ? b : a;
    a = up ? mn : mx;
    b = up ? mx : mn;
}

// R18 (validated R9: -13us issue): ascending-only CE with key-inversion
// normalization — sorted permutation BIT-IDENTICAL at half the CE cost.
__device__ __forceinline__ void cea(unsigned &a, unsigned &b) {
    unsigned mn = (a < b) ? a : b;
    unsigned mx = (a < b) ? b : a;
    a = mn; b = mx;
}

__device__ __forceinline__ void merge8a(unsigned* r) {
    cea(r[0], r[4]); cea(r[1], r[5]); cea(r[2], r[6]); cea(r[3], r[7]);
    cea(r[0], r[2]); cea(r[1], r[3]); cea(r[4], r[6]); cea(r[5], r[7]);
    cea(r[0], r[1]); cea(r[2], r[3]); cea(r[4], r[5]); cea(r[6], r[7]);
}

__device__ __forceinline__ void shfl_ce(unsigned* r, int d, bool keepMin) {
    #pragma unroll
    for (int q = 0; q < V; ++q) {
        unsigned p = __shfl_xor(r[q], d, 64);
        bool lt = r[q] < p;
        r[q] = (lt == keepMin) ? r[q] : p;
    }
}

// next block head after (lane, d) within lanes [.., bEnd); bEnd*V if none
__device__ __forceinline__ int next_head_p(const unsigned* sU,
                                           const unsigned char* sBeg,
                                           const unsigned char* sEnd,
                                           int lane, int d, int bEnd)
{
    if (d + 1 < (int)sEnd[lane]) return upH(sU[(d + 1) * NT + lane]);
    for (int l = lane + 1; l < bEnd; ++l)
        if (sBeg[l] != sEnd[l]) return upH(sU[(int)sBeg[l] * NT + l]);
    return bEnd << 3;   // bEnd * V
}

// ============================================================================
// R29 == R28 resubmit (R18 bench was the session's third broker infra
// failure; this source is byte-identical to R16's kernel, which RAN and
// PASSED at 200us ctr — a comment edit cannot break a container).
// R28 == R25/R16: validated best (200us ctr, zero spill).
//   R17 (NT=512,V=4) regressed 200->305: halving the per-thread register
//   chain DOUBLED the cross-thread structure (6 LDS exchanges/12 barriers
//   vs 3/5; 9-level merge tree with 512-lane serial scans). Theory revised:
//   the binding latency is cross-thread exchange + serial-merge structure,
//   which V=8/NT=256 minimizes per element. Config axes all measured:
//   launch-bounds (R0/R1/R3/R5/R7/R8/R9), spill-vs-occupancy (R9/R10),
//   LDS-vs-reg (R4), sync granularity (R15/R16), decomposition (R17).
//   Ceiling arithmetic: pure VALU issue ~56us; pipe-occupied 144us (dep
//   bubbles in bitonic CE/shfl chains); barrier/mem stall ~56us. Further
//   gains require replacing the bitonic sort itself (radix/counting) — a
//   rewrite, not a tuning step.
// Structure: idx-embedded qkeys; ascending-only normalized sort; load-time
// orig keys in s_kx; searchless scatter unsort via s_inv; zero-scratch
// expansion; rank = exp(theta)[moments] x blockscale[bwd]; wave-local
// merge sync lev0-5; ph1-row L2 prefetch; firstEx barrier peel.
// ============================================================================
__global__ void __launch_bounds__(NT, 6)
fused_kernel(const float* __restrict__ x1, const float* __restrict__ x2,
             float* __restrict__ out)
{
    __shared__ unsigned       s_kx[N + (N >> 5)];  // orig keys -> governing -> scales
    __shared__ unsigned       s_u [N + (N >> 5)];  // sort exchange -> PAV stacks
    __shared__ unsigned short s_inv[N];            // orig idx -> sorted pos
    __shared__ unsigned char  sBeg[NT], sEnd[NT];
    __shared__ float          s_red[NT / 64][5];
    __shared__ unsigned       swF[NT / 64];
    __shared__ int            swB[NT / 64];

    float* s_kxf = (float*)s_kx;

    const int p    = blockIdx.x;
    const int tid  = threadIdx.x;
    const int lane = tid & 63;
    const int wid  = tid >> 6;

    float S1 = 0.f, Q1 = 0.f, S2 = 0.f, Q2 = 0.f, P = 0.f;
    float rv1[V];

    for (int ph = 0; ph < 2; ++ph) {
        const float* __restrict__ x = ph ? x2 : x1;
        const size_t base = (size_t)p * N;

        // ---- load; orig full keys -> s_kx (own cells); qkeys -> r ----
        const float4* __restrict__ xv = (const float4*)(x + base + tid * V);
        float4 a0 = xv[0], a1 = xv[1];

        if (ph == 0) {
            // L2 prefetch of the ph1 row: touch + sink, no live state.
            const float4* __restrict__ pv = (const float4*)(x2 + base + tid * V);
            float4 p0 = pv[0], p1 = pv[1];
            asm volatile("" :: "v"(p0.x), "v"(p0.w), "v"(p1.x), "v"(p1.w));
        }

        const int bse = tid * V;
        unsigned dk[V];
        dk[0] = desc_key(a0.x * 10.0f); dk[1] = desc_key(a0.y * 10.0f);
        dk[2] = desc_key(a0.z * 10.0f); dk[3] = desc_key(a0.w * 10.0f);
        dk[4] = desc_key(a1.x * 10.0f); dk[5] = desc_key(a1.y * 10.0f);
        dk[6] = desc_key(a1.z * 10.0f); dk[7] = desc_key(a1.w * 10.0f);
        unsigned r[V];
        #pragma unroll
        for (int q = 0; q < V; ++q) {
            s_kx[pidx(bse + q)] = dk[q];
            r[q] = ((dk[q] + 0x400u) & 0xFFFFF800u) | (unsigned)(bse + q);
        }

        // ---- bitonic sort: k=2,4,8 (compile-time directions) ----
        ceu(r[0], r[1], true);  ceu(r[2], r[3], false);
        ceu(r[4], r[5], true);  ceu(r[6], r[7], false);
        ceu(r[0], r[2], true);  ceu(r[1], r[3], true);
        ceu(r[4], r[6], false); ceu(r[5], r[7], false);
        ceu(r[0], r[1], true);  ceu(r[2], r[3], true);
        ceu(r[4], r[5], false); ceu(r[6], r[7], false);

        // normalized space for the k=8 completion (dir bit = tid&1)
        unsigned m = ((tid & 1) == 0) ? 0u : 0xFFFFFFFFu;
        #pragma unroll
        for (int q = 0; q < V; ++q) r[q] ^= m;
        merge8a(r);

        bool firstEx = true;
        #pragma unroll
        for (int kk = 4; kk <= 11; ++kk) {
            const unsigned mn_ = ((tid & (1 << (kk - 3))) == 0) ? 0u : 0xFFFFFFFFu;
            const unsigned dm = m ^ mn_;
            m = mn_;
            #pragma unroll
            for (int q = 0; q < V; ++q) r[q] ^= dm;
            #pragma unroll
            for (int jb = kk - 1; jb >= 3; --jb) {
                const int d = 1 << (jb - 3);
                if (d >= 64) {
                    if (!firstEx) __syncthreads();   // peel: first exchange's
                    firstEx = false;                 // buffer has no prior readers
                    #pragma unroll
                    for (int q = 0; q < V; ++q) s_u[pidx(tid * V + q)] = r[q];
                    __syncthreads();
                    const bool keepMin = ((tid & d) == 0);
                    const int ptid = tid ^ d;
                    #pragma unroll
                    for (int q = 0; q < V; ++q) {
                        unsigned pv = s_u[pidx(ptid * V + q)];
                        bool lt = r[q] < pv;
                        r[q] = (lt == keepMin) ? r[q] : pv;
                    }
                } else {
                    shfl_ce(r, d, (tid & d) == 0);
                }
            }
            merge8a(r);
        }
        // m ends at 0: keys in plain space, fully ascending-sorted.

        __syncthreads();   // drain last exchange readers (s_u reused next)

        // ---- PAV phase 1: true thetas via idx gather; inv-perm scatter ----
        {
            unsigned fkv[V];
            #pragma unroll
            for (int k = 0; k < V; ++k) {
                const int idx = (int)(r[k] & 0x7FFu);
                fkv[k] = s_kx[pidx(idx)];                    // 8-way ILP gather
                s_inv[idx] = (unsigned short)(bse + k);      // inverse perm
            }
            float eY[V];
            #pragma unroll
            for (int k = 0; k < V; ++k) eY[k] = __expf(decode_key(fkv[k]));

            int   sp = 0;
            float t0Y = 0.f, t1Y = 0.f;
            int   t0h = 0,   t1h = 0;
            #pragma unroll
            for (int k = 0; k < V; ++k) {
                const int j = bse + k;
                float cY = eY[k];
                int   ch = j;
                while (sp > 0) {
                    float cW = (float)wsum(ch, j);
                    float tW = (float)wsum(t0h, ch - 1);
                    if (t0Y * cW > cY * tW) break;        // strictly decreasing
                    cY += t0Y; ch = t0h;
                    --sp;
                    t0Y = t1Y; t0h = t1h;
                    if (sp > 1) {
                        unsigned u = s_u[(sp - 2) * NT + tid];
                        t1Y = upY(u); t1h = upH(u);
                    }
                }
                s_u[sp * NT + tid] = packYH(cY, ch);
                t1Y = t0Y; t1h = t0h;
                t0Y = cY;  t0h = ch;
                ++sp;
            }
            sBeg[tid] = 0; sEnd[tid] = (unsigned char)sp;
        }
        // PAV-1 state consumed by lev 0-5 is wave-local (regions <= 1 wave,
        // wave-aligned). Cross-wave readers covered by the real barriers
        // below. Compiler fence only:
        WAVE_FENCE();

        // ---- PAV phase 2: merge tree, 8 levels ----
        // lev 0-5: regions wave-contained -> WAVE_FENCE between levels.
        // lev 6,7: cross-wave regions -> real __syncthreads before them,
        // and one after the loop (expansion reads any lane's column).
        for (int lev = 0; lev < 8; ++lev) {
            const int g = 1 << lev;
            if ((tid & (2 * g - 1)) == 0) {
                const int a = tid, mid = tid + g, b = tid + 2 * g;
                int l0 = mid - 1;
                while (l0 >= a && sBeg[l0] == sEnd[l0]) --l0;
                int l1 = mid;
                while (l1 < b && sBeg[l1] == sEnd[l1]) ++l1;
                if (l0 >= a && l1 < b) {
                    int d0 = (int)sEnd[l0] - 1;
                    unsigned tu = s_u[d0 * NT + l0];
                    float tY = upY(tu); int th_ = upH(tu);
                    int te = (mid << 3) - 1;
                    int d1 = (int)sBeg[l1];
                    unsigned cu = s_u[d1 * NT + l1];
                    float cY = upY(cu); int ch = upH(cu);
                    int ce = next_head_p(s_u, sBeg, sEnd, l1, d1, b) - 1;
                    if (!(tY * (float)wsum(ch, ce) > cY * (float)wsum(th_, te))) {
                        sBeg[l1] = (unsigned char)(d1 + 1);   // consume G1 front
                        for (;;) {
                            if (l0 >= a &&
                                !(tY * (float)wsum(ch, ce) > cY * (float)wsum(th_, te))) {
                                cY += tY; ch = th_;           // absorb G0 top
                                sEnd[l0] = (unsigned char)((int)sEnd[l0] - 1);
                                if (sBeg[l0] == sEnd[l0]) {
                                    do { --l0; } while (l0 >= a && sBeg[l0] == sEnd[l0]);
                                }
                                if (l0 >= a) {
                                    int dd = (int)sEnd[l0] - 1;
                                    unsigned uu = s_u[dd * NT + l0];
                                    tY = upY(uu); te = th_ - 1; th_ = upH(uu);
                                }
                                continue;
                            }
                            while (l1 < b && sBeg[l1] == sEnd[l1]) ++l1;
                            if (l1 < b) {                      // absorb next G1 block?
                                int dn = (int)sBeg[l1];
                                unsigned nu = s_u[dn * NT + l1];
                                float nY = upY(nu); int nh = upH(nu);
                                int ne = next_head_p(s_u, sBeg, sEnd, l1, dn, b) - 1;
                                if (!(cY * (float)wsum(nh, ne) > nY * (float)wsum(ch, ce))) {
                                    cY += nY; ce = ne;
                                    sBeg[l1] = (unsigned char)(dn + 1);
                                    continue;
                                }
                            }
                            break;
                        }
                        int lh = ch >> 3;                      // push at head's lane
                        if (ch >= (mid << 3)) {                // head in G1 -> front
                            int nb = (int)sBeg[lh] - 1;
                            sBeg[lh] = (unsigned char)nb;
                            s_u[nb * NT + lh] = packYH(cY, ch);
                        } else {                               // head in G0 -> tail
                            int nb2 = (int)sEnd[lh];
                            s_u[nb2 * NT + lh] = packYH(cY, ch);
                            sEnd[lh] = (unsigned char)(nb2 + 1);
                        }
                    }
                }
            }
            if (lev >= 5) __syncthreads();   // before lev6, lev7, and after lev7
            else          WAVE_FENCE();      // wave-local levels: free fence
        }

        // ---- divergence-free expansion (stacks read directly from s_u) ----
        const int b0 = sBeg[tid], b1 = sEnd[tid];
        unsigned myLast  = (b1 > b0) ? s_u[(b1 - 1) * NT + tid] : INVALID_P;
        int      myFirst = (b1 > b0) ? upH(s_u[b0 * NT + tid]) : N;

        // forward wave scan: rightmost valid packed entry among lanes <= lane
        unsigned fv = myLast;
        #pragma unroll
        for (int off = 1; off < 64; off <<= 1) {
            unsigned o = (unsigned)__shfl_up((int)fv, off);
            if (fv == INVALID_P) fv = o;
        }
        unsigned cF = (unsigned)__shfl_up((int)fv, 1);
        if (lane == 0) cF = INVALID_P;
        // backward wave scan: leftmost head among lanes >= lane
        int bv = myFirst;
        #pragma unroll
        for (int off = 1; off < 64; off <<= 1) {
            int o = __shfl_down(bv, off);
            if (bv == N) bv = o;
        }
        int cB = __shfl_down(bv, 1);
        if (lane == 63) cB = N;
        if (lane == 63) swF[wid] = fv;
        if (lane == 0)  swB[wid] = bv;
        __syncthreads();
        if (cF == INVALID_P)
            for (int w = wid - 1; w >= 0; --w)
                if (swF[w] != INVALID_P) { cF = swF[w]; break; }
        if (cB == N)
            for (int w = wid + 1; w < NT / 64; ++w)
                if (swB[w] != N) { cB = swB[w]; break; }

        // fwd pass: governing packed (h,Y) per position -> s_kx (keys dead)
        {
            int dptr = b0;
            int nxtOwn = (dptr < b1) ? upH(s_u[dptr * NT + tid]) : N;
            unsigned cur = cF;
            #pragma unroll
            for (int q = 0; q < V; ++q) {
                int j = bse + q;
                if (j == nxtOwn) {
                    cur = s_u[dptr * NT + tid];
                    ++dptr;
                    nxtOwn = (dptr < b1) ? upH(s_u[dptr * NT + tid]) : N;
                }
                s_kx[pidx(j)] = cur;
            }
        }
        // bwd pass: block SCALE c = W/Y written IN PLACE over governing.
        // (exp(theta) re-attached in moments pass — bit-identical product.)
        {
            int dptr2 = b1 - 1;
            int h2 = (dptr2 >= b0) ? upH(s_u[dptr2 * NT + tid]) : -1;
            int nxt = cB;
            #pragma unroll
            for (int q = V - 1; q >= 0; --q) {
                int j = bse + q;
                int e = nxt - 1;
                unsigned cu = s_kx[pidx(j)];
                s_kxf[pidx(j)] = (float)wsum(upH(cu), e) / upY(cu);
                if (j == h2) {
                    nxt = j; --dptr2;
                    h2 = (dptr2 >= b0) ? upH(s_u[dptr2 * NT + tid]) : -1;
                }
            }
        }
        __syncthreads();

        // ---- moments: own-origin gather; rank = exp(theta_own) * scale ----
        {
            float4 c0 = xv[0], c1 = xv[1];
            float xx[V] = {c0.x, c0.y, c0.z, c0.w, c1.x, c1.y, c1.z, c1.w};
            #pragma unroll
            for (int q = 0; q < V; ++q) {
                int jq = (int)s_inv[bse + q];
                float rv = __expf(xx[q] * 10.0f) * s_kxf[pidx(jq)];
                if (ph == 0) {
                    rv1[q] = rv;
                    S1 += rv; Q1 += rv * rv;
                } else {
                    S2 += rv; Q2 += rv * rv; P += rv1[q] * rv;
                }
            }
        }
        __syncthreads();   // protect s_kx/s_u/s_inv before next phase
    }

    // ---- block reduction of the 5 moments ----
    #pragma unroll
    for (int off = 32; off > 0; off >>= 1) {
        S1 += __shfl_down(S1, off);
        Q1 += __shfl_down(Q1, off);
        S2 += __shfl_down(S2, off);
        Q2 += __shfl_down(Q2, off);
        P  += __shfl_down(P,  off);
    }
    if (lane == 0) {
        s_red[wid][0] = S1; s_red[wid][1] = Q1; s_red[wid][2] = S2;
        s_red[wid][3] = Q2; s_red[wid][4] = P;
    }
    __syncthreads();
    if (tid == 0) {
        for (int w = 1; w < NT / 64; ++w) {
            S1 += s_red[w][0]; Q1 += s_red[w][1]; S2 += s_red[w][2];
            Q2 += s_red[w][3]; P  += s_red[w][4];
        }
        const float inv_n = 1.0f / (float)N;
        float num = P  - S1 * S2 * inv_n;
        float d1  = Q1 - S1 * S1 * inv_n;
        float d2  = Q2 - S2 * S2 * inv_n;
        out[p] = 1.0f - num / sqrtf(d1 * d2);
    }
}

extern "C" void kernel_launch(void* const* d_in, const int* in_sizes, int n_in,
                              void* d_out, int out_size, void* d_ws, size_t ws_size,
                              hipStream_t stream) {
    const float* x1 = (const float*)d_in[0];
    const float* x2 = (const float*)d_in[1];
    float* out = (float*)d_out;
    const int nrows = in_sizes[0] / N;        // 4096 row pairs
    fused_kernel<<<nrows, NT, 0, stream>>>(x1, x2, out);
}